// Round 9
// baseline (1406.873 us; speedup 1.0000x reference)
//
#include <hip/hip_runtime.h>
#include <math.h>

#define NN 100000
#define HH 128
#define NCLS 10
#define NGRAPH 256
#define EPSLN 1e-5f
#define NB 196          // ceil(100000/512) buckets of 512 nodes
#define NBLK 256        // blocks for hist/scatter passes
#define NREP 8          // LDS replicas for hist/scatter contention

typedef __attribute__((ext_vector_type(8))) short short8;
typedef __attribute__((ext_vector_type(4))) float f32x4;

static __device__ __forceinline__ unsigned short f2bf(float f){
  unsigned u = __float_as_uint(f);
  u = u + 0x7fffu + ((u >> 16) & 1u);   // round-to-nearest-even
  return (unsigned short)(u >> 16);
}
static __device__ __forceinline__ float bf2f(unsigned short h){
  return __uint_as_float(((unsigned)h) << 16);
}
static __device__ __forceinline__ float bfx(unsigned v){
  return __uint_as_float(v << 16);
}
static __device__ __forceinline__ float bfy(unsigned v){
  return __uint_as_float(v & 0xffff0000u);
}

// ---------------- Bucketed CSR build ----------------
__global__ __launch_bounds__(1024) void bucket_hist(
    const int* __restrict__ dst, int E,
    int* __restrict__ gbucket, int* __restrict__ blkbase)
{
  __shared__ int lh[NREP*NB];
  int tid = threadIdx.x;
  for (int i = tid; i < NREP*NB; i += 1024) lh[i] = 0;
  __syncthreads();
  int rep = (tid >> 7) & (NREP-1);
  int* lhr = &lh[rep*NB];
  int per = (E + gridDim.x - 1) / gridDim.x;
  int s = blockIdx.x * per, e = min(E, s + per);
  for (int j = s + tid; j < e; j += 1024)
    atomicAdd(&lhr[dst[j] >> 9], 1);
  __syncthreads();
  for (int i = tid; i < NREP*NB; i += 1024){
    int r = i / NB, bkt = i - r*NB;
    blkbase[((size_t)blockIdx.x*NREP + r)*NB + bkt] = atomicAdd(&gbucket[bkt], lh[i]);
  }
}

// Fused: bucket scan + stats/params/counter init + colsum + weight transpose.
__global__ __launch_bounds__(256) void misc_prep(
    const int* __restrict__ gbucket, int* __restrict__ bucket_base, int E,
    int* __restrict__ row_ptr, int N,
    float* __restrict__ params, float* __restrict__ stats, int* __restrict__ counters,
    const float* __restrict__ lin1W, const float* __restrict__ convW,
    unsigned short* __restrict__ WtAll, float* __restrict__ csums)
{
  int b = blockIdx.x;
  if (b == 0){
    if (threadIdx.x == 0){
      int run = 0;
      for (int i = 0; i < NB; i++){ bucket_base[i] = run; run += gbucket[i]; }
      bucket_base[NB] = run;
      row_ptr[N] = E;
      params[0] = 0.f;   // mu for layer-0 conv (no LN yet)
      params[1] = 1.f;   // rsig
      for (int i = 0; i < 6; i++) stats[i] = 0.f;
      for (int i = 0; i < 3; i++) counters[i] = 0;
    }
  } else if (b <= 3){
    int m = b - 1;
    if (threadIdx.x < HH){
      const float* w = convW + (size_t)m*HH*HH;
      float s = 0.f;
      for (int k = 0; k < HH; k++) s += w[k*HH + threadIdx.x];
      csums[m*HH + threadIdx.x] = s;
    }
  } else {
    int m = b - 4;   // 0..3: lin1, conv0, conv1, conv2
    const float* srcW = (m == 0) ? lin1W : convW + (size_t)(m-1)*HH*HH;
    unsigned short* dstW = WtAll + (size_t)m*HH*HH;
    for (int i = threadIdx.x; i < HH*HH; i += 256){
      int k = i >> 7, nn2 = i & 127;
      dstW[nn2*HH + k] = f2bf(srcW[i]);
    }
  }
}

// Pass B: scatter packed (dloc 9b | src 23b), 8-replica cursors.
__global__ __launch_bounds__(1024) void bucket_scatter(
    const int* __restrict__ src, const int* __restrict__ dst, int E,
    const int* __restrict__ bucket_base, const int* __restrict__ blkbase,
    unsigned* __restrict__ ebuf)
{
  __shared__ int lcur[NREP*NB];
  int tid = threadIdx.x;
  for (int i = tid; i < NREP*NB; i += 1024){
    int r = i / NB, bkt = i - r*NB;
    lcur[i] = bucket_base[bkt] + blkbase[((size_t)blockIdx.x*NREP + r)*NB + bkt];
  }
  __syncthreads();
  int rep = (tid >> 7) & (NREP-1);
  int* lcr = &lcur[rep*NB];
  int per = (E + gridDim.x - 1) / gridDim.x;
  int s = blockIdx.x * per, e = min(E, s + per);
  for (int j = s + tid; j < e; j += 1024){
    int d = dst[j];
    int p = atomicAdd(&lcr[d >> 9], 1);
    ebuf[p] = (((unsigned)(d & 511)) << 23) | (unsigned)src[j];
  }
}

// Pass C: per bucket: local deg + scan -> row_ptr/dinv, fill csr window.
__global__ __launch_bounds__(1024) void bucket_fill(
    const unsigned* __restrict__ ebuf,
    const int* __restrict__ bucket_base, int N,
    int* __restrict__ row_ptr, float* __restrict__ dinv,
    int* __restrict__ csr)
{
  __shared__ int ldeg[512];
  __shared__ int lscan[512];
  __shared__ int lcur[512];
  int b = blockIdx.x, tid = threadIdx.x;
  int node0 = b << 9;
  int nn = min(512, N - node0);
  for (int i = tid; i < 512; i += 1024) ldeg[i] = 0;
  __syncthreads();
  int s = bucket_base[b], e = bucket_base[b + 1];
  for (int j = s + tid; j < e; j += 1024)
    atomicAdd(&ldeg[ebuf[j] >> 23], 1);
  __syncthreads();
  if (tid < 512) lscan[tid] = ldeg[tid];
  __syncthreads();
  for (int off = 1; off < 512; off <<= 1){
    int v = (tid < 512 && tid >= off) ? lscan[tid - off] : 0;
    __syncthreads();
    if (tid < 512) lscan[tid] += v;
    __syncthreads();
  }
  if (tid < nn){
    int rp = s + lscan[tid] - ldeg[tid];
    row_ptr[node0 + tid] = rp;
    lcur[tid] = rp;
    dinv[node0 + tid] = rsqrtf((float)(ldeg[tid] + 1));  // +1 self-loop
  }
  __syncthreads();
  for (int j = s + tid; j < e; j += 1024){
    unsigned pk = ebuf[j];
    int p = atomicAdd(&lcur[pk >> 23], 1);
    csr[p] = (int)(pk & 0x7fffffu);
  }
}

// ---------------- MFMA GEMM: out(bf16) = epilogue(A @ W) ----------------
// mode 0: standard [row][128] layout (bufA).
// mode 1: SLICE-MAJOR gather-table layout: [slice=col>>4][node][col&15],
//         each slice = contiguous n*32B region (L2-resident per agg pass).
__global__ __launch_bounds__(256) void gemm_mfma(
    const float* __restrict__ A32, const unsigned short* __restrict__ A16,
    const unsigned short* __restrict__ Wt,
    const float* __restrict__ bias, const float* __restrict__ dinv,
    const float* __restrict__ params, const float* __restrict__ colsum,
    unsigned short* __restrict__ out, int n, int mode)
{
  __shared__ unsigned short As[128*128];  // [row][k] swizzled 16B slots
  __shared__ unsigned short Ws[128*128];  // [n][k]   swizzled 16B slots
  int tid = threadIdx.x;
  int rb = blockIdx.x * 128;

  #pragma unroll
  for (int rep = 0; rep < 8; rep++){
    int idx = rep*256 + tid;
    int r = idx >> 4, j = idx & 15;
    uint4 v = *(const uint4*)&Wt[r*HH + j*8];
    *(uint4*)&Ws[r*128 + ((j ^ (r & 7)) << 3)] = v;
  }
  if (mode == 1){
    #pragma unroll
    for (int rep = 0; rep < 8; rep++){
      int idx = rep*256 + tid;
      int r = idx >> 4, j = idx & 15;
      int row = rb + r;
      uint4 v = make_uint4(0,0,0,0);
      if (row < n) v = *(const uint4*)&A16[(size_t)row*HH + j*8];
      *(uint4*)&As[r*128 + ((j ^ (r & 7)) << 3)] = v;
    }
  } else {
    #pragma unroll
    for (int rep = 0; rep < 16; rep++){
      int idx = rep*256 + tid;
      int r = idx >> 5, j4 = idx & 31;
      int row = rb + r;
      float4 v = make_float4(0,0,0,0);
      if (row < n) v = *(const float4*)&A32[(size_t)row*HH + j4*4];
      uint2 pk;
      pk.x = (unsigned)f2bf(v.x) | ((unsigned)f2bf(v.y) << 16);
      pk.y = (unsigned)f2bf(v.z) | ((unsigned)f2bf(v.w) << 16);
      int uidx = r*128 + ((((j4 >> 1) ^ (r & 7)) << 3)) + (j4 & 1)*4;
      *(uint2*)&As[uidx] = pk;
    }
  }
  __syncthreads();

  int l = tid & 63, w = tid >> 6;
  int lr = l & 15, lk = l >> 4;
  f32x4 acc[2][8];
  #pragma unroll
  for (int mt = 0; mt < 2; mt++)
    #pragma unroll
    for (int nt = 0; nt < 8; nt++) acc[mt][nt] = (f32x4)(0.f);

  #pragma unroll
  for (int kc = 0; kc < 4; kc++){
    short8 af[2];
    #pragma unroll
    for (int mt = 0; mt < 2; mt++){
      int row = w*32 + mt*16 + lr;
      af[mt] = *(const short8*)&As[row*128 + (((kc*4 + lk) ^ (row & 7)) << 3)];
    }
    #pragma unroll
    for (int nt = 0; nt < 8; nt++){
      int col = nt*16 + lr;
      short8 bf = *(const short8*)&Ws[col*128 + (((kc*4 + lk) ^ (col & 7)) << 3)];
      acc[0][nt] = __builtin_amdgcn_mfma_f32_16x16x32_bf16(af[0], bf, acc[0][nt], 0, 0, 0);
      acc[1][nt] = __builtin_amdgcn_mfma_f32_16x16x32_bf16(af[1], bf, acc[1][nt], 0, 0, 0);
    }
  }

  float mu = 0.f, rsig = 1.f;
  if (mode == 1){ mu = params[0]; rsig = params[1]; }
  float dvs[2][4];
  #pragma unroll
  for (int mt = 0; mt < 2; mt++)
    #pragma unroll
    for (int r = 0; r < 4; r++){
      int row = rb + w*32 + mt*16 + lk*4 + r;
      dvs[mt][r] = (mode == 1 && row < n) ? dinv[row] : 0.f;
    }
  #pragma unroll
  for (int nt = 0; nt < 8; nt++){
    int col = nt*16 + lr;
    float cs = (mode == 1) ? colsum[col] : 0.f;
    float bb = (mode == 0) ? bias[col] : 0.f;
    #pragma unroll
    for (int mt = 0; mt < 2; mt++){
      #pragma unroll
      for (int r = 0; r < 4; r++){
        int row = rb + w*32 + mt*16 + lk*4 + r;
        if (row < n){
          float a = acc[mt][nt][r];
          if (mode == 0){
            out[(size_t)row*HH + col] = f2bf(fmaxf(a + bb, 0.f));
          } else {
            float vv = dvs[mt][r] * rsig * (a - mu*cs);
            // sliced: [slice=nt][row][lr]  (16 bf16 = 32B per node per slice)
            out[((size_t)nt*n + row)*16 + lr] = f2bf(vv);
          }
        }
      }
    }
  }
}

// -------- Aggregation: 8 x 32B feature slices, slice-major table -----------
// grid.x = 8*nb4, slice = blockIdx.x/nb4 (slice-major execution). Table is
// [slice][node][8 u32]: each slice = contiguous n*32B = 3.2MB, fits every
// XCD's 4MB L2. Wave = node-slice. Lanes: e = l>>3 (edge octet), f = l&7.
// csr int4 loads require j%4==0 -> scalar prologue.
__global__ __launch_bounds__(256) void aggregate(
    const unsigned* __restrict__ hw, const int* __restrict__ row_ptr,
    const int* __restrict__ csr, const float* __restrict__ dinv,
    const float* __restrict__ bias, unsigned* __restrict__ hout,
    float2* __restrict__ partials, int n, int nb4)
{
  int bx = blockIdx.x;
  int slice = bx / nb4;
  int nblk  = bx - slice*nb4;
  int wid = __builtin_amdgcn_readfirstlane(threadIdx.x >> 6);
  int node = nblk*4 + wid;
  if (node >= n) return;
  int l = threadIdx.x & 63;
  int e = l >> 3;                 // edge subgroup 0..7
  int f = l & 7;                  // u32 slot within slice (2 bf16 features)
  unsigned sb = (unsigned)slice * (unsigned)n;  // slice base row

  float ax = 0.f, ay = 0.f;
  if (e == 0){                    // self loop, counted once
    unsigned sv = hw[(size_t)(sb + node)*8 + f];
    ax = bfx(sv); ay = bfy(sv);
  }
  int s0 = row_ptr[node], s1 = row_ptr[node+1];
  int j = s0;
  int jal = (s0 + 3) & ~3;        // align for int4 csr loads
  if (jal > s1) jal = s1;
  int pre = jal - j;              // 0..3
  if (e < pre){
    unsigned v = hw[(size_t)(sb + csr[j + e])*8 + f];
    ax += bfx(v); ay += bfy(v);
  }
  j = jal;
  #define SEL4(q) ((e3==0)?(q).x:(e3==1)?(q).y:(e3==2)?(q).z:(q).w)
  for (; j + 16 <= s1; j += 16){
    int4 q0 = *(const int4*)&csr[j];
    int4 q1 = *(const int4*)&csr[j+4];
    int4 q2 = *(const int4*)&csr[j+8];
    int4 q3 = *(const int4*)&csr[j+12];
    int e3 = e & 3;
    int a0 = SEL4(q0), a1 = SEL4(q1), b0 = SEL4(q2), b1 = SEL4(q3);
    int idA = (e < 4) ? a0 : a1;            // edge j+e
    int idB = (e < 4) ? b0 : b1;            // edge j+8+e
    unsigned vA = hw[(size_t)(sb + idA)*8 + f];
    unsigned vB = hw[(size_t)(sb + idB)*8 + f];
    ax += bfx(vA) + bfx(vB);
    ay += bfy(vA) + bfy(vB);
  }
  for (; j + 8 <= s1; j += 8){
    int4 q0 = *(const int4*)&csr[j];
    int4 q1 = *(const int4*)&csr[j+4];
    int e3 = e & 3;
    int a0 = SEL4(q0), a1 = SEL4(q1);
    int idA = (e < 4) ? a0 : a1;
    unsigned v = hw[(size_t)(sb + idA)*8 + f];
    ax += bfx(v); ay += bfy(v);
  }
  #undef SEL4
  int rem = s1 - j;               // 0..7
  if (e < rem){
    unsigned v = hw[(size_t)(sb + csr[j + e])*8 + f];
    ax += bfx(v); ay += bfy(v);
  }
  // combine the 8 edge-subgroups (l bits 3..5 encode e)
  ax += __shfl_xor(ax, 8, 64); ax += __shfl_xor(ax, 16, 64); ax += __shfl_xor(ax, 32, 64);
  ay += __shfl_xor(ay, 8, 64); ay += __shfl_xor(ay, 16, 64); ay += __shfl_xor(ay, 32, 64);

  float dv = dinv[node];
  float2 bb = ((const float2*)bias)[slice*8 + f];
  float rx = fmaxf(fmaf(dv, ax, bb.x), 0.f);
  float ry = fmaxf(fmaf(dv, ay, bb.y), 0.f);

  // LN partial over this slice's 16 features (reduce across f)
  float s = rx + ry, q = rx*rx + ry*ry;
  s += __shfl_xor(s, 1, 64); s += __shfl_xor(s, 2, 64); s += __shfl_xor(s, 4, 64);
  q += __shfl_xor(q, 1, 64); q += __shfl_xor(q, 2, 64); q += __shfl_xor(q, 4, 64);

  if (e == 0){
    // standard layout write-back for next GEMM / pooling
    hout[(size_t)node*64 + slice*8 + f] = (unsigned)f2bf(rx) | ((unsigned)f2bf(ry) << 16);
    if (f == 0) partials[(size_t)slice*n + node] = make_float2(s, q);
  }
}

// Fused LN stats reduction over 8N slice-partials: last block computes mu/rsig.
__global__ __launch_bounds__(256) void finalize_ln(
    const float2* __restrict__ partials, int n2, float* __restrict__ stats,
    int* __restrict__ counter, float* __restrict__ params)
{
  int tid = threadIdx.x;
  float s = 0.f, q = 0.f;
  for (int i = blockIdx.x*256 + tid; i < n2; i += gridDim.x*256){
    float2 p = partials[i];
    s += p.x; q += p.y;
  }
  #pragma unroll
  for (int off = 32; off > 0; off >>= 1){
    s += __shfl_xor(s, off, 64);
    q += __shfl_xor(q, off, 64);
  }
  __shared__ float ssm[4], qsm[4];
  int wave = tid >> 6, lane = tid & 63;
  if (lane == 0){ ssm[wave] = s; qsm[wave] = q; }
  __syncthreads();
  if (tid == 0){
    atomicAdd(&stats[0], ssm[0]+ssm[1]+ssm[2]+ssm[3]);
    atomicAdd(&stats[1], qsm[0]+qsm[1]+qsm[2]+qsm[3]);
    __threadfence();
    int done = atomicAdd(counter, 1);
    if (done == (int)gridDim.x - 1){
      float S = atomicAdd(&stats[0], 0.f);
      float Q = atomicAdd(&stats[1], 0.f);
      const float inv = 1.f / ((float)NN * (float)HH);
      float mu = S * inv;
      float var = Q * inv - mu*mu;
      params[0] = mu;
      params[1] = rsqrtf(var + EPSLN);
    }
  }
}

// ---------------- Pool + MLP + log_softmax (node-parallel) ----------------
__global__ __launch_bounds__(1024) void pool_mlp(
    const unsigned* __restrict__ h, const int* __restrict__ batch,
    const float* __restrict__ params, const float* __restrict__ W1,
    const float* __restrict__ b1, const float* __restrict__ W2,
    const float* __restrict__ b2, float* __restrict__ out, int n)
{
  __shared__ float W1s[128*128];
  __shared__ float2 psum[16][64];
  __shared__ float pooled[128];
  __shared__ float gact[128];
  __shared__ float sc[16];
  __shared__ int se[2];
  int g = blockIdx.x, tid = threadIdx.x;

  #pragma unroll
  for (int rep = 0; rep < 4; rep++){
    int i = rep*1024 + tid;
    *(float4*)&W1s[i*4] = *(const float4*)&W1[i*4];
  }
  if (tid < 2){
    int v = g + tid;
    int lo = 0, hi = n;
    while (lo < hi){ int mid = (lo+hi) >> 1; if (batch[mid] < v) lo = mid+1; else hi = mid; }
    se[tid] = lo;
  }
  __syncthreads();
  int start = se[0], end = se[1];
  int w = tid >> 6, l = tid & 63;
  float sx = 0.f, sy = 0.f;
  for (int v = start + w; v < end; v += 16){
    unsigned u = h[v*64 + l];
    sx += __uint_as_float(u << 16);
    sy += __uint_as_float(u & 0xffff0000u);
  }
  psum[w][l] = make_float2(sx, sy);
  __syncthreads();
  if (tid < 64){
    float ax = 0.f, ay = 0.f;
    #pragma unroll
    for (int ww = 0; ww < 16; ww++){
      float2 p = psum[ww][tid];
      ax += p.x; ay += p.y;
    }
    float cnt = (float)((end - start) > 0 ? (end - start) : 1);
    float mu = params[0], rs = params[1];
    pooled[tid*2]   = rs * (ax / cnt - mu);
    pooled[tid*2+1] = rs * (ay / cnt - mu);
  }
  __syncthreads();
  if (tid < 128){
    float a = b1[tid];
    for (int k = 0; k < HH; k++) a = fmaf(pooled[k], W1s[k*HH + tid], a);
    gact[tid] = fmaxf(a, 0.f);
  }
  __syncthreads();
  if (tid < NCLS){
    float s = b2[tid];
    for (int k = 0; k < HH; k++) s = fmaf(gact[k], W2[k*NCLS + tid], s);
    sc[tid] = s;
  }
  __syncthreads();
  if (tid == 0){
    float m = sc[0];
    for (int j = 1; j < NCLS; j++) m = fmaxf(m, sc[j]);
    float lse = 0.f;
    for (int j = 0; j < NCLS; j++) lse += expf(sc[j] - m);
    lse = logf(lse);
    for (int j = 0; j < NCLS; j++) out[g*NCLS + j] = sc[j] - m - lse;
  }
}

// ---------------- launch ----------------
extern "C" void kernel_launch(void* const* d_in, const int* in_sizes, int n_in,
                              void* d_out, int out_size, void* d_ws, size_t ws_size,
                              hipStream_t stream)
{
  const float* x      = (const float*)d_in[0];
  const int*   ei     = (const int*)d_in[1];
  const int*   batch  = (const int*)d_in[2];
  const float* lin1_W = (const float*)d_in[3];
  const float* lin1_b = (const float*)d_in[4];
  const float* conv_W = (const float*)d_in[5];
  const float* conv_b = (const float*)d_in[6];
  const float* mlp_W1 = (const float*)d_in[7];
  const float* mlp_b1 = (const float*)d_in[8];
  const float* mlp_W2 = (const float*)d_in[9];
  const float* mlp_b2 = (const float*)d_in[10];

  const int N = in_sizes[2];      // 100000
  const int E = in_sizes[1] / 2;  // 3200000

  char* ws = (char*)d_ws;
  size_t off = 0;
  auto alloc = [&](size_t bytes)->char*{
    char* p = ws + off; off += (bytes + 255) & ~(size_t)255; return p;
  };
  unsigned short* bufA = (unsigned short*)alloc((size_t)N*HH*2); // h (bf16, std layout)
  unsigned short* bufB = (unsigned short*)alloc((size_t)N*HH*2); // gather table (sliced)
  unsigned short* WtAll= (unsigned short*)alloc((size_t)4*HH*HH*2);
  int*      csr     = (int*)     alloc((size_t)E*4);
  unsigned* ebuf    = (unsigned*)alloc((size_t)E*4);
  int*      row_ptr = (int*)     alloc((size_t)(N+1)*4);
  float*    dinv    = (float*)   alloc((size_t)N*4);
  int*      gbucket = (int*)     alloc((size_t)NB*4);
  int*      bucket_base = (int*) alloc((size_t)(NB+1)*4);
  int*      blkbase = (int*)     alloc((size_t)NBLK*NREP*NB*4);
  float*    params  = (float*)   alloc(256);
  float*    stats   = (float*)   alloc(256);
  int*      counters= (int*)     alloc(256);
  float*    csums   = (float*)   alloc(3*HH*4);
  float2*   partials= (float2*)  alloc((size_t)N*8*sizeof(float2));

  const int* srcp = ei;
  const int* dstp = ei + E;

  hipMemsetAsync(gbucket, 0, (size_t)NB*4, stream);
  bucket_hist<<<NBLK, 1024, 0, stream>>>(dstp, E, gbucket, blkbase);
  misc_prep<<<8, 256, 0, stream>>>(gbucket, bucket_base, E, row_ptr, N,
                                   params, stats, counters,
                                   lin1_W, conv_W, WtAll, csums);
  bucket_scatter<<<NBLK, 1024, 0, stream>>>(srcp, dstp, E, bucket_base, blkbase, ebuf);
  bucket_fill<<<NB, 1024, 0, stream>>>(ebuf, bucket_base, N, row_ptr, dinv, csr);

  int gblocks = (N + 127) / 128;
  gemm_mfma<<<gblocks, 256, 0, stream>>>(x, nullptr, WtAll, lin1_b,
                                         nullptr, nullptr, nullptr, bufA, N, 0);
  int nb4 = (N + 3) / 4;
  for (int i = 0; i < 3; i++){
    gemm_mfma<<<gblocks, 256, 0, stream>>>(nullptr, bufA, WtAll + (size_t)(i+1)*HH*HH,
                                           nullptr, dinv, params + 2*i, csums + i*HH,
                                           bufB, N, 1);
    aggregate<<<8*nb4, 256, 0, stream>>>((const unsigned*)bufB, row_ptr, csr, dinv,
                                         conv_b + i*HH, (unsigned*)bufA,
                                         partials, N, nb4);
    finalize_ln<<<64, 256, 0, stream>>>(partials, 8*N, stats + 2*i,
                                        counters + i, params + 2*(i+1));
  }
  pool_mlp<<<NGRAPH, 1024, 0, stream>>>((const unsigned*)bufA, batch, params + 6,
                                        mlp_W1, mlp_b1, mlp_W2, mlp_b2,
                                        (float*)d_out, N);
}

// Round 10
// 585.573 us; speedup vs baseline: 2.4026x; 2.4026x over previous
//
#include <hip/hip_runtime.h>
#include <math.h>

#define NN 100000
#define HH 128
#define NCLS 10
#define NGRAPH 256
#define EPSLN 1e-5f
#define NB 196          // ceil(100000/512) buckets of 512 nodes
#define NBLK 256        // blocks for hist/scatter passes
#define NREP 8          // LDS replicas for hist/scatter contention

typedef __attribute__((ext_vector_type(8))) short short8;
typedef __attribute__((ext_vector_type(4))) float f32x4;

static __device__ __forceinline__ unsigned short f2bf(float f){
  unsigned u = __float_as_uint(f);
  u = u + 0x7fffu + ((u >> 16) & 1u);   // round-to-nearest-even
  return (unsigned short)(u >> 16);
}
static __device__ __forceinline__ float bf2f(unsigned short h){
  return __uint_as_float(((unsigned)h) << 16);
}
static __device__ __forceinline__ float bfx(unsigned v){
  return __uint_as_float(v << 16);
}
static __device__ __forceinline__ float bfy(unsigned v){
  return __uint_as_float(v & 0xffff0000u);
}

// ---------------- Bucketed CSR build ----------------
__global__ __launch_bounds__(1024) void bucket_hist(
    const int* __restrict__ dst, int E,
    int* __restrict__ gbucket, int* __restrict__ blkbase)
{
  __shared__ int lh[NREP*NB];
  int tid = threadIdx.x;
  for (int i = tid; i < NREP*NB; i += 1024) lh[i] = 0;
  __syncthreads();
  int rep = (tid >> 7) & (NREP-1);
  int* lhr = &lh[rep*NB];
  int per = (E + gridDim.x - 1) / gridDim.x;
  int s = blockIdx.x * per, e = min(E, s + per);
  for (int j = s + tid; j < e; j += 1024)
    atomicAdd(&lhr[dst[j] >> 9], 1);
  __syncthreads();
  for (int i = tid; i < NREP*NB; i += 1024){
    int r = i / NB, bkt = i - r*NB;
    blkbase[((size_t)blockIdx.x*NREP + r)*NB + bkt] = atomicAdd(&gbucket[bkt], lh[i]);
  }
}

// Fused: bucket scan + stats/params/counter init + colsum + weight transpose.
__global__ __launch_bounds__(256) void misc_prep(
    const int* __restrict__ gbucket, int* __restrict__ bucket_base, int E,
    int* __restrict__ row_ptr, int N,
    float* __restrict__ params, float* __restrict__ stats, int* __restrict__ counters,
    const float* __restrict__ lin1W, const float* __restrict__ convW,
    unsigned short* __restrict__ WtAll, float* __restrict__ csums)
{
  int b = blockIdx.x;
  if (b == 0){
    if (threadIdx.x == 0){
      int run = 0;
      for (int i = 0; i < NB; i++){ bucket_base[i] = run; run += gbucket[i]; }
      bucket_base[NB] = run;
      row_ptr[N] = E;
      params[0] = 0.f;   // mu for layer-0 conv (no LN yet)
      params[1] = 1.f;   // rsig
      for (int i = 0; i < 6; i++) stats[i] = 0.f;
      for (int i = 0; i < 3; i++) counters[i] = 0;
    }
  } else if (b <= 3){
    int m = b - 1;
    if (threadIdx.x < HH){
      const float* w = convW + (size_t)m*HH*HH;
      float s = 0.f;
      for (int k = 0; k < HH; k++) s += w[k*HH + threadIdx.x];
      csums[m*HH + threadIdx.x] = s;
    }
  } else {
    int m = b - 4;   // 0..3: lin1, conv0, conv1, conv2
    const float* srcW = (m == 0) ? lin1W : convW + (size_t)(m-1)*HH*HH;
    unsigned short* dstW = WtAll + (size_t)m*HH*HH;
    for (int i = threadIdx.x; i < HH*HH; i += 256){
      int k = i >> 7, nn2 = i & 127;
      dstW[nn2*HH + k] = f2bf(srcW[i]);
    }
  }
}

// Pass B: scatter packed (dloc 9b | src 23b), 8-replica cursors.
__global__ __launch_bounds__(1024) void bucket_scatter(
    const int* __restrict__ src, const int* __restrict__ dst, int E,
    const int* __restrict__ bucket_base, const int* __restrict__ blkbase,
    unsigned* __restrict__ ebuf)
{
  __shared__ int lcur[NREP*NB];
  int tid = threadIdx.x;
  for (int i = tid; i < NREP*NB; i += 1024){
    int r = i / NB, bkt = i - r*NB;
    lcur[i] = bucket_base[bkt] + blkbase[((size_t)blockIdx.x*NREP + r)*NB + bkt];
  }
  __syncthreads();
  int rep = (tid >> 7) & (NREP-1);
  int* lcr = &lcur[rep*NB];
  int per = (E + gridDim.x - 1) / gridDim.x;
  int s = blockIdx.x * per, e = min(E, s + per);
  for (int j = s + tid; j < e; j += 1024){
    int d = dst[j];
    int p = atomicAdd(&lcr[d >> 9], 1);
    ebuf[p] = (((unsigned)(d & 511)) << 23) | (unsigned)src[j];
  }
}

// Pass C: per bucket: local deg + scan -> row_ptr/dinv, fill csr window.
__global__ __launch_bounds__(1024) void bucket_fill(
    const unsigned* __restrict__ ebuf,
    const int* __restrict__ bucket_base, int N,
    int* __restrict__ row_ptr, float* __restrict__ dinv,
    int* __restrict__ csr)
{
  __shared__ int ldeg[512];
  __shared__ int lscan[512];
  __shared__ int lcur[512];
  int b = blockIdx.x, tid = threadIdx.x;
  int node0 = b << 9;
  int nn = min(512, N - node0);
  for (int i = tid; i < 512; i += 1024) ldeg[i] = 0;
  __syncthreads();
  int s = bucket_base[b], e = bucket_base[b + 1];
  for (int j = s + tid; j < e; j += 1024)
    atomicAdd(&ldeg[ebuf[j] >> 23], 1);
  __syncthreads();
  if (tid < 512) lscan[tid] = ldeg[tid];
  __syncthreads();
  for (int off = 1; off < 512; off <<= 1){
    int v = (tid < 512 && tid >= off) ? lscan[tid - off] : 0;
    __syncthreads();
    if (tid < 512) lscan[tid] += v;
    __syncthreads();
  }
  if (tid < nn){
    int rp = s + lscan[tid] - ldeg[tid];
    row_ptr[node0 + tid] = rp;
    lcur[tid] = rp;
    dinv[node0 + tid] = rsqrtf((float)(ldeg[tid] + 1));  // +1 self-loop
  }
  __syncthreads();
  for (int j = s + tid; j < e; j += 1024){
    unsigned pk = ebuf[j];
    int p = atomicAdd(&lcur[pk >> 23], 1);
    csr[p] = (int)(pk & 0x7fffffu);
  }
}

// ---------------- MFMA GEMM: out(bf16) = epilogue(A @ W) ----------------
__global__ __launch_bounds__(256) void gemm_mfma(
    const float* __restrict__ A32, const unsigned short* __restrict__ A16,
    const unsigned short* __restrict__ Wt,
    const float* __restrict__ bias, const float* __restrict__ dinv,
    const float* __restrict__ params, const float* __restrict__ colsum,
    unsigned short* __restrict__ out, int n, int mode)
{
  __shared__ unsigned short As[128*128];  // [row][k] swizzled 16B slots
  __shared__ unsigned short Ws[128*128];  // [n][k]   swizzled 16B slots
  int tid = threadIdx.x;
  int rb = blockIdx.x * 128;

  #pragma unroll
  for (int rep = 0; rep < 8; rep++){
    int idx = rep*256 + tid;
    int r = idx >> 4, j = idx & 15;
    uint4 v = *(const uint4*)&Wt[r*HH + j*8];
    *(uint4*)&Ws[r*128 + ((j ^ (r & 7)) << 3)] = v;
  }
  if (mode == 1){
    #pragma unroll
    for (int rep = 0; rep < 8; rep++){
      int idx = rep*256 + tid;
      int r = idx >> 4, j = idx & 15;
      int row = rb + r;
      uint4 v = make_uint4(0,0,0,0);
      if (row < n) v = *(const uint4*)&A16[(size_t)row*HH + j*8];
      *(uint4*)&As[r*128 + ((j ^ (r & 7)) << 3)] = v;
    }
  } else {
    #pragma unroll
    for (int rep = 0; rep < 16; rep++){
      int idx = rep*256 + tid;
      int r = idx >> 5, j4 = idx & 31;
      int row = rb + r;
      float4 v = make_float4(0,0,0,0);
      if (row < n) v = *(const float4*)&A32[(size_t)row*HH + j4*4];
      uint2 pk;
      pk.x = (unsigned)f2bf(v.x) | ((unsigned)f2bf(v.y) << 16);
      pk.y = (unsigned)f2bf(v.z) | ((unsigned)f2bf(v.w) << 16);
      int uidx = r*128 + ((((j4 >> 1) ^ (r & 7)) << 3)) + (j4 & 1)*4;
      *(uint2*)&As[uidx] = pk;
    }
  }
  __syncthreads();

  int l = tid & 63, w = tid >> 6;
  int lr = l & 15, lk = l >> 4;
  f32x4 acc[2][8];
  #pragma unroll
  for (int mt = 0; mt < 2; mt++)
    #pragma unroll
    for (int nt = 0; nt < 8; nt++) acc[mt][nt] = (f32x4)(0.f);

  #pragma unroll
  for (int kc = 0; kc < 4; kc++){
    short8 af[2];
    #pragma unroll
    for (int mt = 0; mt < 2; mt++){
      int row = w*32 + mt*16 + lr;
      af[mt] = *(const short8*)&As[row*128 + (((kc*4 + lk) ^ (row & 7)) << 3)];
    }
    #pragma unroll
    for (int nt = 0; nt < 8; nt++){
      int col = nt*16 + lr;
      short8 bf = *(const short8*)&Ws[col*128 + (((kc*4 + lk) ^ (col & 7)) << 3)];
      acc[0][nt] = __builtin_amdgcn_mfma_f32_16x16x32_bf16(af[0], bf, acc[0][nt], 0, 0, 0);
      acc[1][nt] = __builtin_amdgcn_mfma_f32_16x16x32_bf16(af[1], bf, acc[1][nt], 0, 0, 0);
    }
  }

  float mu = 0.f, rsig = 1.f;
  if (mode == 1){ mu = params[0]; rsig = params[1]; }
  float dvs[2][4];
  #pragma unroll
  for (int mt = 0; mt < 2; mt++)
    #pragma unroll
    for (int r = 0; r < 4; r++){
      int row = rb + w*32 + mt*16 + lk*4 + r;
      dvs[mt][r] = (mode == 1 && row < n) ? dinv[row] : 0.f;
    }
  #pragma unroll
  for (int nt = 0; nt < 8; nt++){
    int col = nt*16 + lr;
    float cs = (mode == 1) ? colsum[col] : 0.f;
    float bb = (mode == 0) ? bias[col] : 0.f;
    #pragma unroll
    for (int mt = 0; mt < 2; mt++){
      #pragma unroll
      for (int r = 0; r < 4; r++){
        int row = rb + w*32 + mt*16 + lk*4 + r;
        if (row < n){
          float a = acc[mt][nt][r];
          float vv = (mode == 0) ? fmaxf(a + bb, 0.f)
                                 : dvs[mt][r] * rsig * (a - mu*cs);
          out[(size_t)row*HH + col] = f2bf(vv);
        }
      }
    }
  }
}

// ---------------- Aggregation: wave-per-node, u32-packed bf16 gathers ------
// Best-measured variant (R5): scalar csr loads (node wave-uniform via
// readfirstlane), 16-deep software prefetch of indices, 16 gathers in
// flight per wave, full 256B row per edge.
__global__ __launch_bounds__(256) void aggregate(
    const unsigned* __restrict__ hw, const int* __restrict__ row_ptr,
    const int* __restrict__ csr, const float* __restrict__ dinv,
    const float* __restrict__ bias, unsigned* __restrict__ hout,
    float2* __restrict__ partials, int n)
{
  int wid = __builtin_amdgcn_readfirstlane(threadIdx.x >> 6);
  int node = blockIdx.x * 4 + wid;
  if (node >= n) return;
  int l = threadIdx.x & 63;               // lane l owns features 2l, 2l+1
  int selfoff = node*64 + l;
  unsigned selfv = hw[selfoff];
  float ax = bfx(selfv);
  float ay = bfy(selfv);
  int s0 = row_ptr[node], s1 = row_ptr[node+1];
  int j = s0;
  if (j + 16 <= s1){
    int cur[16];
    #pragma unroll
    for (int u = 0; u < 16; u++) cur[u] = csr[j+u];
    while (true){
      unsigned v[16];
      #pragma unroll
      for (int u = 0; u < 16; u++) v[u] = hw[cur[u]*64 + l];
      int jn = j + 16;
      bool more = (jn + 16 <= s1);
      int nxt[16];
      if (more){
        #pragma unroll
        for (int u = 0; u < 16; u++) nxt[u] = csr[jn+u];
      }
      #pragma unroll
      for (int u = 0; u < 16; u++){
        ax += bfx(v[u]);
        ay += bfy(v[u]);
      }
      j = jn;
      if (!more) break;
      #pragma unroll
      for (int u = 0; u < 16; u++) cur[u] = nxt[u];
    }
  }
  for (; j + 4 <= s1; j += 4){
    int i0 = csr[j], i1 = csr[j+1], i2 = csr[j+2], i3 = csr[j+3];
    unsigned v0 = hw[i0*64+l], v1 = hw[i1*64+l], v2 = hw[i2*64+l], v3 = hw[i3*64+l];
    ax += (bfx(v0) + bfx(v1)) + (bfx(v2) + bfx(v3));
    ay += (bfy(v0) + bfy(v1)) + (bfy(v2) + bfy(v3));
  }
  for (; j < s1; j++){
    unsigned v = hw[csr[j]*64 + l];
    ax += bfx(v);
    ay += bfy(v);
  }
  float dv = dinv[node];
  float2 bb = ((const float2*)bias)[l];
  float rx = fmaxf(fmaf(dv, ax, bb.x), 0.f);
  float ry = fmaxf(fmaf(dv, ay, bb.y), 0.f);
  hout[selfoff] = (unsigned)f2bf(rx) | ((unsigned)f2bf(ry) << 16);

  float s = rx + ry, q = rx*rx + ry*ry;
  #pragma unroll
  for (int off = 32; off > 0; off >>= 1){
    s += __shfl_xor(s, off, 64);
    q += __shfl_xor(q, off, 64);
  }
  if (l == 0) partials[node] = make_float2(s, q);
}

// Fused LN stats reduction: last block computes mu/rsig.
__global__ __launch_bounds__(256) void finalize_ln(
    const float2* __restrict__ partials, int n2, float* __restrict__ stats,
    int* __restrict__ counter, float* __restrict__ params)
{
  int tid = threadIdx.x;
  float s = 0.f, q = 0.f;
  for (int i = blockIdx.x*256 + tid; i < n2; i += gridDim.x*256){
    float2 p = partials[i];
    s += p.x; q += p.y;
  }
  #pragma unroll
  for (int off = 32; off > 0; off >>= 1){
    s += __shfl_xor(s, off, 64);
    q += __shfl_xor(q, off, 64);
  }
  __shared__ float ssm[4], qsm[4];
  int wave = tid >> 6, lane = tid & 63;
  if (lane == 0){ ssm[wave] = s; qsm[wave] = q; }
  __syncthreads();
  if (tid == 0){
    atomicAdd(&stats[0], ssm[0]+ssm[1]+ssm[2]+ssm[3]);
    atomicAdd(&stats[1], qsm[0]+qsm[1]+qsm[2]+qsm[3]);
    __threadfence();
    int done = atomicAdd(counter, 1);
    if (done == (int)gridDim.x - 1){
      float S = atomicAdd(&stats[0], 0.f);   // device-scope read-back
      float Q = atomicAdd(&stats[1], 0.f);
      const float inv = 1.f / ((float)NN * (float)HH);
      float mu = S * inv;
      float var = Q * inv - mu*mu;
      params[0] = mu;
      params[1] = rsqrtf(var + EPSLN);
    }
  }
}

// ---------------- Pool + MLP + log_softmax (node-parallel) ----------------
__global__ __launch_bounds__(1024) void pool_mlp(
    const unsigned* __restrict__ h, const int* __restrict__ batch,
    const float* __restrict__ params, const float* __restrict__ W1,
    const float* __restrict__ b1, const float* __restrict__ W2,
    const float* __restrict__ b2, float* __restrict__ out, int n)
{
  __shared__ float W1s[128*128];
  __shared__ float2 psum[16][64];
  __shared__ float pooled[128];
  __shared__ float gact[128];
  __shared__ float sc[16];
  __shared__ int se[2];
  int g = blockIdx.x, tid = threadIdx.x;

  #pragma unroll
  for (int rep = 0; rep < 4; rep++){
    int i = rep*1024 + tid;
    *(float4*)&W1s[i*4] = *(const float4*)&W1[i*4];
  }
  if (tid < 2){
    int v = g + tid;
    int lo = 0, hi = n;
    while (lo < hi){ int mid = (lo+hi) >> 1; if (batch[mid] < v) lo = mid+1; else hi = mid; }
    se[tid] = lo;
  }
  __syncthreads();
  int start = se[0], end = se[1];
  int w = tid >> 6, l = tid & 63;
  float sx = 0.f, sy = 0.f;
  for (int v = start + w; v < end; v += 16){
    unsigned u = h[v*64 + l];
    sx += bfx(u);
    sy += bfy(u);
  }
  psum[w][l] = make_float2(sx, sy);
  __syncthreads();
  if (tid < 64){
    float ax = 0.f, ay = 0.f;
    #pragma unroll
    for (int ww = 0; ww < 16; ww++){
      float2 p = psum[ww][tid];
      ax += p.x; ay += p.y;
    }
    float cnt = (float)((end - start) > 0 ? (end - start) : 1);
    float mu = params[0], rs = params[1];
    pooled[tid*2]   = rs * (ax / cnt - mu);
    pooled[tid*2+1] = rs * (ay / cnt - mu);
  }
  __syncthreads();
  if (tid < 128){
    float a = b1[tid];
    for (int k = 0; k < HH; k++) a = fmaf(pooled[k], W1s[k*HH + tid], a);
    gact[tid] = fmaxf(a, 0.f);
  }
  __syncthreads();
  if (tid < NCLS){
    float s = b2[tid];
    for (int k = 0; k < HH; k++) s = fmaf(gact[k], W2[k*NCLS + tid], s);
    sc[tid] = s;
  }
  __syncthreads();
  if (tid == 0){
    float m = sc[0];
    for (int j = 1; j < NCLS; j++) m = fmaxf(m, sc[j]);
    float lse = 0.f;
    for (int j = 0; j < NCLS; j++) lse += expf(sc[j] - m);
    lse = logf(lse);
    for (int j = 0; j < NCLS; j++) out[g*NCLS + j] = sc[j] - m - lse;
  }
}

// ---------------- launch ----------------
extern "C" void kernel_launch(void* const* d_in, const int* in_sizes, int n_in,
                              void* d_out, int out_size, void* d_ws, size_t ws_size,
                              hipStream_t stream)
{
  const float* x      = (const float*)d_in[0];
  const int*   ei     = (const int*)d_in[1];
  const int*   batch  = (const int*)d_in[2];
  const float* lin1_W = (const float*)d_in[3];
  const float* lin1_b = (const float*)d_in[4];
  const float* conv_W = (const float*)d_in[5];
  const float* conv_b = (const float*)d_in[6];
  const float* mlp_W1 = (const float*)d_in[7];
  const float* mlp_b1 = (const float*)d_in[8];
  const float* mlp_W2 = (const float*)d_in[9];
  const float* mlp_b2 = (const float*)d_in[10];

  const int N = in_sizes[2];      // 100000
  const int E = in_sizes[1] / 2;  // 3200000

  char* ws = (char*)d_ws;
  size_t off = 0;
  auto alloc = [&](size_t bytes)->char*{
    char* p = ws + off; off += (bytes + 255) & ~(size_t)255; return p;
  };
  unsigned short* bufA = (unsigned short*)alloc((size_t)N*HH*2); // h (bf16)
  unsigned short* bufB = (unsigned short*)alloc((size_t)N*HH*2); // gather table
  unsigned short* WtAll= (unsigned short*)alloc((size_t)4*HH*HH*2);
  int*      csr     = (int*)     alloc((size_t)E*4);
  unsigned* ebuf    = (unsigned*)alloc((size_t)E*4);
  int*      row_ptr = (int*)     alloc((size_t)(N+1)*4);
  float*    dinv    = (float*)   alloc((size_t)N*4);
  int*      gbucket = (int*)     alloc((size_t)NB*4);
  int*      bucket_base = (int*) alloc((size_t)(NB+1)*4);
  int*      blkbase = (int*)     alloc((size_t)NBLK*NREP*NB*4);
  float*    params  = (float*)   alloc(256);
  float*    stats   = (float*)   alloc(256);
  int*      counters= (int*)     alloc(256);
  float*    csums   = (float*)   alloc(3*HH*4);
  float2*   partials= (float2*)  alloc((size_t)N*sizeof(float2));

  const int* srcp = ei;
  const int* dstp = ei + E;

  hipMemsetAsync(gbucket, 0, (size_t)NB*4, stream);
  bucket_hist<<<NBLK, 1024, 0, stream>>>(dstp, E, gbucket, blkbase);
  misc_prep<<<8, 256, 0, stream>>>(gbucket, bucket_base, E, row_ptr, N,
                                   params, stats, counters,
                                   lin1_W, conv_W, WtAll, csums);
  bucket_scatter<<<NBLK, 1024, 0, stream>>>(srcp, dstp, E, bucket_base, blkbase, ebuf);
  bucket_fill<<<NB, 1024, 0, stream>>>(ebuf, bucket_base, N, row_ptr, dinv, csr);

  int gblocks = (N + 127) / 128;
  gemm_mfma<<<gblocks, 256, 0, stream>>>(x, nullptr, WtAll, lin1_b,
                                         nullptr, nullptr, nullptr, bufA, N, 0);
  for (int i = 0; i < 3; i++){
    gemm_mfma<<<gblocks, 256, 0, stream>>>(nullptr, bufA, WtAll + (size_t)(i+1)*HH*HH,
                                           nullptr, dinv, params + 2*i, csums + i*HH,
                                           bufB, N, 1);
    aggregate<<<(N+3)/4, 256, 0, stream>>>((const unsigned*)bufB, row_ptr, csr, dinv,
                                           conv_b + i*HH, (unsigned*)bufA, partials, N);
    finalize_ln<<<64, 256, 0, stream>>>(partials, N, stats + 2*i,
                                        counters + i, params + 2*(i+1));
  }
  pool_mlp<<<NGRAPH, 1024, 0, stream>>>((const unsigned*)bufA, batch, params + 6,
                                        mlp_W1, mlp_b1, mlp_W2, mlp_b2,
                                        (float*)d_out, N);
}